// Round 1
// baseline (598.200 us; speedup 1.0000x reference)
//
#include <hip/hip_runtime.h>
#include <stdint.h>

#define SEQ 2048
#define HIDDEN 1024
#define NHEADS 16
#define HDIM 64
#define MTOT 8192  // B*SEQ

typedef __bf16 bf16x8 __attribute__((ext_vector_type(8)));
typedef unsigned short u16x8 __attribute__((ext_vector_type(8)));
typedef float f32x4 __attribute__((ext_vector_type(4)));

#define GAS __attribute__((address_space(1)))
#define LAS __attribute__((address_space(3)))

__device__ __forceinline__ unsigned short bf16_rne(float f) {
  union { float f; unsigned int u; } v; v.f = f;
  return (unsigned short)((v.u + 0x7fffu + ((v.u >> 16) & 1u)) >> 16);
}

__device__ __forceinline__ void gload_lds16(const unsigned short* g, unsigned short* l) {
  __builtin_amdgcn_global_load_lds((GAS void*)(unsigned short*)g, (LAS void*)l, 16, 0, 0);
}

// ---------------- fp32 -> bf16 conversion (vectorized, memory-bound) -------
__global__ __launch_bounds__(256) void cvt_f32_bf16(const float* __restrict__ in,
                                                    unsigned short* __restrict__ out) {
  int i = blockIdx.x * 256 + threadIdx.x;
  float4 v = ((const float4*)in)[i];
  ushort4 o;
  o.x = bf16_rne(v.x); o.y = bf16_rne(v.y);
  o.z = bf16_rne(v.z); o.w = bf16_rne(v.w);
  ((ushort4*)out)[i] = o;
}

// ---------------- m97-style GEMM: C[M,N] = A[M,K] * W[N,K]^T + bias --------
// 128x128 tile, BK=32, 4 waves, each wave 64x64 (4x4 of 16x16x32 mfma).
template <bool BF16_OUT>
__global__ __launch_bounds__(256) void gemm_bt(const unsigned short* __restrict__ A,
                                               const unsigned short* __restrict__ W,
                                               const float* __restrict__ bias,
                                               void* __restrict__ Cv,
                                               int M, int N, int K) {
  __shared__ unsigned short As[128 * 32];
  __shared__ unsigned short Bs[128 * 32];
  const int tid = threadIdx.x;
  const int lane = tid & 63, w = tid >> 6;
  const int quad = lane >> 4, ln = lane & 15;
  const int wm = w & 1, wn = w >> 1;
  const int mBase = blockIdx.y * 128, nBase = blockIdx.x * 128;

  f32x4 acc[4][4];
  f32x4 zero = {0.f, 0.f, 0.f, 0.f};
#pragma unroll
  for (int i = 0; i < 4; i++)
#pragma unroll
    for (int j = 0; j < 4; j++) acc[i][j] = zero;

  // staging element offsets: 256 threads x 16B covers half a tile; 2 rounds.
  const int e0 = tid * 8;
  const int e1 = (256 + tid) * 8;
  const int r0 = e0 >> 5, c0 = e0 & 31;
  const int r1 = e1 >> 5, c1 = e1 & 31;
  const unsigned short* Ap0 = A + (size_t)(mBase + r0) * K + c0;
  const unsigned short* Ap1 = A + (size_t)(mBase + r1) * K + c1;
  const unsigned short* Wp0 = W + (size_t)(nBase + r0) * K + c0;
  const unsigned short* Wp1 = W + (size_t)(nBase + r1) * K + c1;

  for (int k0 = 0; k0 < K; k0 += 32) {
    gload_lds16(Ap0 + k0, &As[e0]);
    gload_lds16(Ap1 + k0, &As[e1]);
    gload_lds16(Wp0 + k0, &Bs[e0]);
    gload_lds16(Wp1 + k0, &Bs[e1]);
    __syncthreads();
    u16x8 af[4], bfr[4];
#pragma unroll
    for (int mi = 0; mi < 4; mi++)
      af[mi] = *(const u16x8*)&As[(wm * 64 + mi * 16 + ln) * 32 + quad * 8];
#pragma unroll
    for (int ni = 0; ni < 4; ni++)
      bfr[ni] = *(const u16x8*)&Bs[(wn * 64 + ni * 16 + ln) * 32 + quad * 8];
#pragma unroll
    for (int mi = 0; mi < 4; mi++)
#pragma unroll
      for (int ni = 0; ni < 4; ni++)
        acc[mi][ni] = __builtin_amdgcn_mfma_f32_16x16x32_bf16(
            __builtin_bit_cast(bf16x8, af[mi]), __builtin_bit_cast(bf16x8, bfr[ni]),
            acc[mi][ni], 0, 0, 0);
    __syncthreads();
  }

#pragma unroll
  for (int ni = 0; ni < 4; ni++) {
    const int col = nBase + wn * 64 + ni * 16 + ln;
    const float bv = bias[col];
#pragma unroll
    for (int mi = 0; mi < 4; mi++) {
      const int row = mBase + wm * 64 + mi * 16 + quad * 4;
#pragma unroll
      for (int r = 0; r < 4; r++) {
        float v = acc[mi][ni][r] + bv;
        if (BF16_OUT)
          ((unsigned short*)Cv)[(size_t)(row + r) * N + col] = bf16_rne(v);
        else
          ((float*)Cv)[(size_t)(row + r) * N + col] = v;
      }
    }
  }
}

// ---------------- flash attention: per (b,h), online softmax ---------------
// Block: 128 Q rows (4 waves x 32 rows). K/V tiles of 64 keys.
// C-layout (16x16 mfma): col=lane&15, row=quad*4+reg.  A-layout: A[m=lane&15][k=quad*8+j].
__global__ __launch_bounds__(256) void attn_kernel(const unsigned short* __restrict__ Q,
                                                   const unsigned short* __restrict__ K,
                                                   const unsigned short* __restrict__ V,
                                                   unsigned short* __restrict__ X) {
  __shared__ unsigned short Pbuf[4][32 * 72];  // per-wave P (32x64, stride 72: 16B-aligned rows)
  __shared__ unsigned short Vt[2][64 * 72];    // double-buffered V^T [d][key], stride 72

  const int tid = threadIdx.x, lane = tid & 63, w = tid >> 6;
  const int quad = lane >> 4, ln = lane & 15;
  const int bh = blockIdx.y, b = bh >> 4, h = bh & 15;
  const size_t base = (size_t)b * SEQ * HIDDEN + (size_t)h * HDIM;
  const unsigned short* Qh = Q + base;
  const unsigned short* Kh = K + base;
  const unsigned short* Vh = V + base;
  const int qrow0 = blockIdx.x * 128 + w * 32;

  // Q fragments resident in registers: A[m=ln][k], 2 m-tiles x 2 k-steps
  u16x8 qf[2][2];
#pragma unroll
  for (int mi = 0; mi < 2; mi++)
#pragma unroll
    for (int kk = 0; kk < 2; kk++)
      qf[mi][kk] = *(const u16x8*)(Qh + (size_t)(qrow0 + mi * 16 + ln) * HIDDEN + kk * 32 + quad * 8);

  f32x4 o[2][4];
  f32x4 zero = {0.f, 0.f, 0.f, 0.f};
#pragma unroll
  for (int mi = 0; mi < 2; mi++)
#pragma unroll
    for (int ni = 0; ni < 4; ni++) o[mi][ni] = zero;
  float mst[2][4], lst[2][4];
#pragma unroll
  for (int mi = 0; mi < 2; mi++)
#pragma unroll
    for (int r = 0; r < 4; r++) { mst[mi][r] = -INFINITY; lst[mi][r] = 0.f; }

  unsigned short* Pw = &Pbuf[w][0];

  for (int kt = 0; kt < SEQ / 64; ++kt) {
    unsigned short* vt = &Vt[kt & 1][0];
    // ---- stage V^T tile: thread (w,lane): key=lane, d-chunk = w*16..w*16+15
    {
      const unsigned short* vp = Vh + (size_t)(kt * 64 + lane) * HIDDEN + w * 16;
      uint4 va = *(const uint4*)vp;
      uint4 vb2 = *(const uint4*)(vp + 8);
      unsigned int vals[8] = {va.x, va.y, va.z, va.w, vb2.x, vb2.y, vb2.z, vb2.w};
#pragma unroll
      for (int i = 0; i < 8; i++) {
        vt[(w * 16 + 2 * i) * 72 + lane] = (unsigned short)(vals[i] & 0xffffu);
        vt[(w * 16 + 2 * i + 1) * 72 + lane] = (unsigned short)(vals[i] >> 16);
      }
    }
    // ---- S = Q K^T (K B-frags straight from global: B[k=d][n=key])
    f32x4 s[2][4];
#pragma unroll
    for (int mi = 0; mi < 2; mi++)
#pragma unroll
      for (int ni = 0; ni < 4; ni++) s[mi][ni] = zero;
#pragma unroll
    for (int ni = 0; ni < 4; ni++)
#pragma unroll
      for (int kk = 0; kk < 2; kk++) {
        u16x8 kf = *(const u16x8*)(Kh + (size_t)(kt * 64 + ni * 16 + ln) * HIDDEN + kk * 32 + quad * 8);
#pragma unroll
        for (int mi = 0; mi < 2; mi++)
          s[mi][ni] = __builtin_amdgcn_mfma_f32_16x16x32_bf16(
              __builtin_bit_cast(bf16x8, qf[mi][kk]), __builtin_bit_cast(bf16x8, kf),
              s[mi][ni], 0, 0, 0);
      }
    // ---- scale 1/sqrt(64)
#pragma unroll
    for (int mi = 0; mi < 2; mi++)
#pragma unroll
      for (int ni = 0; ni < 4; ni++)
#pragma unroll
        for (int r = 0; r < 4; r++) s[mi][ni][r] *= 0.125f;
    // ---- row max (over ni in-reg, then xor-butterfly over 16 lanes of quad)
    float alpha[2][4];
#pragma unroll
    for (int mi = 0; mi < 2; mi++)
#pragma unroll
      for (int r = 0; r < 4; r++) {
        float m0 = fmaxf(fmaxf(s[mi][0][r], s[mi][1][r]), fmaxf(s[mi][2][r], s[mi][3][r]));
#pragma unroll
        for (int d = 1; d < 16; d <<= 1) m0 = fmaxf(m0, __shfl_xor(m0, d));
        float mn = fmaxf(mst[mi][r], m0);
        alpha[mi][r] = __builtin_exp2f((mst[mi][r] - mn) * 1.44269504088896f);
        mst[mi][r] = mn;
      }
    // ---- P = exp(S - m), row sums, state update
#pragma unroll
    for (int mi = 0; mi < 2; mi++)
#pragma unroll
      for (int ni = 0; ni < 4; ni++)
#pragma unroll
        for (int r = 0; r < 4; r++)
          s[mi][ni][r] = __builtin_exp2f((s[mi][ni][r] - mst[mi][r]) * 1.44269504088896f);
#pragma unroll
    for (int mi = 0; mi < 2; mi++)
#pragma unroll
      for (int r = 0; r < 4; r++) {
        float t = s[mi][0][r] + s[mi][1][r] + s[mi][2][r] + s[mi][3][r];
#pragma unroll
        for (int d = 1; d < 16; d <<= 1) t += __shfl_xor(t, d);
        lst[mi][r] = alpha[mi][r] * lst[mi][r] + t;
      }
#pragma unroll
    for (int mi = 0; mi < 2; mi++)
#pragma unroll
      for (int ni = 0; ni < 4; ni++)
#pragma unroll
        for (int r = 0; r < 4; r++) o[mi][ni][r] *= alpha[mi][r];
    // ---- P (C-layout) -> LDS -> A-layout
#pragma unroll
    for (int mi = 0; mi < 2; mi++)
#pragma unroll
      for (int ni = 0; ni < 4; ni++)
#pragma unroll
        for (int r = 0; r < 4; r++)
          Pw[(mi * 16 + quad * 4 + r) * 72 + ni * 16 + ln] = bf16_rne(s[mi][ni][r]);
    __syncthreads();  // Vt staged by all waves; also drains lgkm for Pw
    // ---- O += P V
    u16x8 pf[2][2];
#pragma unroll
    for (int mi = 0; mi < 2; mi++)
#pragma unroll
      for (int kk = 0; kk < 2; kk++)
        pf[mi][kk] = *(const u16x8*)&Pw[(mi * 16 + ln) * 72 + kk * 32 + quad * 8];
#pragma unroll
    for (int ni = 0; ni < 4; ni++)
#pragma unroll
      for (int kk = 0; kk < 2; kk++) {
        u16x8 vfr = *(const u16x8*)&vt[(ni * 16 + ln) * 72 + kk * 32 + quad * 8];
#pragma unroll
        for (int mi = 0; mi < 2; mi++)
          o[mi][ni] = __builtin_amdgcn_mfma_f32_16x16x32_bf16(
              __builtin_bit_cast(bf16x8, pf[mi][kk]), __builtin_bit_cast(bf16x8, vfr),
              o[mi][ni], 0, 0, 0);
      }
  }
  // ---- epilogue: O / l -> X[b*SEQ+row][h*64+d] (bf16)
#pragma unroll
  for (int mi = 0; mi < 2; mi++)
#pragma unroll
    for (int r = 0; r < 4; r++) {
      float inv = 1.0f / lst[mi][r];
      size_t row = (size_t)b * SEQ + qrow0 + mi * 16 + quad * 4 + r;
#pragma unroll
      for (int ni = 0; ni < 4; ni++)
        X[row * HIDDEN + h * HDIM + ni * 16 + ln] = bf16_rne(o[mi][ni][r] * inv);
    }
}

// ---------------------------------------------------------------------------
extern "C" void kernel_launch(void* const* d_in, const int* in_sizes, int n_in,
                              void* d_out, int out_size, void* d_ws, size_t ws_size,
                              hipStream_t stream) {
  const float* q_in = (const float*)d_in[0];
  const float* k_in = (const float*)d_in[1];
  const float* v_in = (const float*)d_in[2];
  const float* wq = (const float*)d_in[3];
  const float* bq = (const float*)d_in[4];
  const float* wk = (const float*)d_in[5];
  const float* bk = (const float*)d_in[6];
  const float* wv = (const float*)d_in[7];
  const float* bv = (const float*)d_in[8];
  const float* wf = (const float*)d_in[9];
  const float* bfb = (const float*)d_in[10];

  const size_t NX = (size_t)MTOT * HIDDEN;    // 8.39M elems
  const size_t NW = (size_t)HIDDEN * HIDDEN;  // 1.05M elems
  unsigned short* Xq = (unsigned short*)d_ws;
  unsigned short* Xk = Xq + NX;
  unsigned short* Xv = Xk + NX;
  unsigned short* Wq = Xv + NX;
  unsigned short* Wk = Wq + NW;
  unsigned short* Wv = Wk + NW;
  unsigned short* Wf = Wv + NW;
  unsigned short* Qb = Wf + NW;
  unsigned short* Kb = Qb + NX;
  unsigned short* Vb = Kb + NX;
  unsigned short* Xo = Vb + NX;  // total ws use: ~126 MB

  cvt_f32_bf16<<<NX / 1024, 256, 0, stream>>>(q_in, Xq);
  cvt_f32_bf16<<<NX / 1024, 256, 0, stream>>>(k_in, Xk);
  cvt_f32_bf16<<<NX / 1024, 256, 0, stream>>>(v_in, Xv);
  cvt_f32_bf16<<<NW / 1024, 256, 0, stream>>>(wq, Wq);
  cvt_f32_bf16<<<NW / 1024, 256, 0, stream>>>(wk, Wk);
  cvt_f32_bf16<<<NW / 1024, 256, 0, stream>>>(wv, Wv);
  cvt_f32_bf16<<<NW / 1024, 256, 0, stream>>>(wf, Wf);

  dim3 gg(HIDDEN / 128, MTOT / 128);  // (8, 64)
  gemm_bt<true><<<gg, 256, 0, stream>>>(Xq, Wq, bq, (void*)Qb, MTOT, HIDDEN, HIDDEN);
  gemm_bt<true><<<gg, 256, 0, stream>>>(Xk, Wk, bk, (void*)Kb, MTOT, HIDDEN, HIDDEN);
  gemm_bt<true><<<gg, 256, 0, stream>>>(Xv, Wv, bv, (void*)Vb, MTOT, HIDDEN, HIDDEN);
  attn_kernel<<<dim3(SEQ / 128, 64), 256, 0, stream>>>(Qb, Kb, Vb, Xo);
  gemm_bt<false><<<gg, 256, 0, stream>>>(Xo, Wf, bfb, d_out, MTOT, HIDDEN, HIDDEN);
}

// Round 2
// 526.592 us; speedup vs baseline: 1.1360x; 1.1360x over previous
//
#include <hip/hip_runtime.h>
#include <stdint.h>

#define SEQ 2048
#define HIDDEN 1024
#define NHEADS 16
#define HDIM 64
#define MTOT 8192  // B*SEQ

typedef __bf16 bf16x8 __attribute__((ext_vector_type(8)));
typedef unsigned short u16x8 __attribute__((ext_vector_type(8)));
typedef float f32x4 __attribute__((ext_vector_type(4)));

#define GAS __attribute__((address_space(1)))
#define LAS __attribute__((address_space(3)))

__device__ __forceinline__ unsigned short bf16_rne(float f) {
  union { float f; unsigned int u; } v; v.f = f;
  return (unsigned short)((v.u + 0x7fffu + ((v.u >> 16) & 1u)) >> 16);
}

__device__ __forceinline__ void gload_lds16(const unsigned short* g, unsigned short* l) {
  __builtin_amdgcn_global_load_lds((GAS void*)(unsigned short*)g, (LAS void*)l, 16, 0, 0);
}

// ---------------- fused fp32 -> bf16 conversions ---------------------------
__global__ __launch_bounds__(256) void cvt3(const float* __restrict__ a,
                                            const float* __restrict__ b,
                                            const float* __restrict__ c,
                                            unsigned short* __restrict__ out,
                                            int perSeg) {
  const int seg = blockIdx.y;
  const float* in = seg == 0 ? a : (seg == 1 ? b : c);
  int i = blockIdx.x * 256 + threadIdx.x;
  float4 v = ((const float4*)in)[i];
  ushort4 o;
  o.x = bf16_rne(v.x); o.y = bf16_rne(v.y);
  o.z = bf16_rne(v.z); o.w = bf16_rne(v.w);
  ((ushort4*)(out + (size_t)seg * perSeg))[i] = o;
}

__global__ __launch_bounds__(256) void cvt4(const float* __restrict__ a,
                                            const float* __restrict__ b,
                                            const float* __restrict__ c,
                                            const float* __restrict__ d,
                                            unsigned short* __restrict__ out,
                                            int perSeg) {
  const int seg = blockIdx.y;
  const float* in = seg == 0 ? a : (seg == 1 ? b : (seg == 2 ? c : d));
  int i = blockIdx.x * 256 + threadIdx.x;
  float4 v = ((const float4*)in)[i];
  ushort4 o;
  o.x = bf16_rne(v.x); o.y = bf16_rne(v.y);
  o.z = bf16_rne(v.z); o.w = bf16_rne(v.w);
  ((ushort4*)(out + (size_t)seg * perSeg))[i] = o;
}

// ---------------- m97-style GEMM: C[M,N] = A[M,K] * W[N,K]^T + bias --------
template <bool BF16_OUT>
__global__ __launch_bounds__(256) void gemm_bt(const unsigned short* __restrict__ A,
                                               const unsigned short* __restrict__ W,
                                               const float* __restrict__ bias,
                                               void* __restrict__ Cv,
                                               int M, int N, int K) {
  __shared__ unsigned short As[128 * 32];
  __shared__ unsigned short Bs[128 * 32];
  const int tid = threadIdx.x;
  const int lane = tid & 63, w = tid >> 6;
  const int quad = lane >> 4, ln = lane & 15;
  const int wm = w & 1, wn = w >> 1;
  const int mBase = blockIdx.y * 128, nBase = blockIdx.x * 128;

  f32x4 acc[4][4];
  f32x4 zero = {0.f, 0.f, 0.f, 0.f};
#pragma unroll
  for (int i = 0; i < 4; i++)
#pragma unroll
    for (int j = 0; j < 4; j++) acc[i][j] = zero;

  const int e0 = tid * 8;
  const int e1 = (256 + tid) * 8;
  const int r0 = e0 >> 5, c0 = e0 & 31;
  const int r1 = e1 >> 5, c1 = e1 & 31;
  const unsigned short* Ap0 = A + (size_t)(mBase + r0) * K + c0;
  const unsigned short* Ap1 = A + (size_t)(mBase + r1) * K + c1;
  const unsigned short* Wp0 = W + (size_t)(nBase + r0) * K + c0;
  const unsigned short* Wp1 = W + (size_t)(nBase + r1) * K + c1;

  for (int k0 = 0; k0 < K; k0 += 32) {
    gload_lds16(Ap0 + k0, &As[e0]);
    gload_lds16(Ap1 + k0, &As[e1]);
    gload_lds16(Wp0 + k0, &Bs[e0]);
    gload_lds16(Wp1 + k0, &Bs[e1]);
    __syncthreads();
    u16x8 af[4], bfr[4];
#pragma unroll
    for (int mi = 0; mi < 4; mi++)
      af[mi] = *(const u16x8*)&As[(wm * 64 + mi * 16 + ln) * 32 + quad * 8];
#pragma unroll
    for (int ni = 0; ni < 4; ni++)
      bfr[ni] = *(const u16x8*)&Bs[(wn * 64 + ni * 16 + ln) * 32 + quad * 8];
#pragma unroll
    for (int mi = 0; mi < 4; mi++)
#pragma unroll
      for (int ni = 0; ni < 4; ni++)
        acc[mi][ni] = __builtin_amdgcn_mfma_f32_16x16x32_bf16(
            __builtin_bit_cast(bf16x8, af[mi]), __builtin_bit_cast(bf16x8, bfr[ni]),
            acc[mi][ni], 0, 0, 0);
    __syncthreads();
  }

#pragma unroll
  for (int ni = 0; ni < 4; ni++) {
    const int col = nBase + wn * 64 + ni * 16 + ln;
    const float bv = bias[col];
#pragma unroll
    for (int mi = 0; mi < 4; mi++) {
      const int row = mBase + wm * 64 + mi * 16 + quad * 4;
#pragma unroll
      for (int r = 0; r < 4; r++) {
        float v = acc[mi][ni][r] + bv;
        if (BF16_OUT)
          ((unsigned short*)Cv)[(size_t)(row + r) * N + col] = bf16_rne(v);
        else
          ((float*)Cv)[(size_t)(row + r) * N + col] = v;
      }
    }
  }
}

// ---------------- V transpose into per-tile, bank-swizzled V^T chunks ------
// Vb[b*SEQ+s][h*64+d]  ->  Vt[tile=(bh*16+kt)][d][granule slot = (key>>3) ^ (d&15)]
// Each tile: 64 d-rows x 128 keys, row = 256 B, 16B granules swizzled.
__global__ __launch_bounds__(256) void transpose_v(const unsigned short* __restrict__ Vb,
                                                   unsigned short* __restrict__ Vt) {
  __shared__ unsigned short L[128 * 88];  // [key][d], stride 88 (176 B: 16B-aligned rows, 12-bank key step)
  const int t = blockIdx.x;  // 1024 tiles
  const int bh = t >> 4, kt = t & 15;
  const int b = bh >> 4, h = bh & 15;
  const int tid = threadIdx.x;
  {
    const int key = tid >> 1, hf = tid & 1;
    const unsigned short* src =
        Vb + ((size_t)(b * SEQ + kt * 128 + key)) * HIDDEN + h * HDIM + hf * 32;
    u16x8 a0 = *(const u16x8*)(src);
    u16x8 a1 = *(const u16x8*)(src + 8);
    u16x8 a2 = *(const u16x8*)(src + 16);
    u16x8 a3 = *(const u16x8*)(src + 24);
    unsigned short* dst = &L[key * 88 + hf * 32];
    *(u16x8*)(dst) = a0;
    *(u16x8*)(dst + 8) = a1;
    *(u16x8*)(dst + 16) = a2;
    *(u16x8*)(dst + 24) = a3;
  }
  __syncthreads();
  // wave w handles key-granules G = w*4..w*4+3 for all 64 d (lane = d)
  const int d = tid & 63, w = tid >> 6;
  unsigned short* out = Vt + (size_t)t * (64 * 128);
#pragma unroll
  for (int g = 0; g < 4; g++) {
    const int G = w * 4 + g;
    u16x8 v;
#pragma unroll
    for (int j = 0; j < 8; j++) v[j] = L[(G * 8 + j) * 88 + d];
    *(u16x8*)(out + d * 128 + ((G ^ (d & 15)) * 8)) = v;
  }
}

// ---------------- flash attention, S^T formulation -------------------------
// Per wave: 32 queries; per block: 128 queries, K-tiles of 128 keys.
// S^T = K·Q^T  (A=K rows, B=Q rows, both straight from global).
// C-layout: col(n)=query=ln, row=key=quad*4+reg  -> column softmax = 2 shfl.
// P^T -> per-wave LDS (b64 packed writes) -> B-frags (b128).  O^T = V^T·P^T,
// V^T A-frags from swizzled LDS tile staged by global_load_lds.
__global__ __launch_bounds__(256, 3) void attn2(const unsigned short* __restrict__ Q,
                                                const unsigned short* __restrict__ K,
                                                const unsigned short* __restrict__ Vt,
                                                unsigned short* __restrict__ X) {
  __shared__ unsigned short VtL[64 * 128];     // 16 KB, swizzled [d][key]
  __shared__ unsigned short Pt2[4][32 * 136];  // per-wave P^T as [q][key], stride 136
  const int tid = threadIdx.x, lane = tid & 63, w = tid >> 6;
  const int quad = lane >> 4, ln = lane & 15;
  const int bh = blockIdx.y, b = bh >> 4, h = bh & 15;
  const size_t base = (size_t)b * SEQ * HIDDEN + (size_t)h * HDIM;
  const unsigned short* Qh = Q + base;
  const unsigned short* Kh = K + base;
  const int qw = blockIdx.x * 128 + w * 32;
  const float C1 = 0.125f * 1.44269504088896f;  // fold 1/sqrt(64) into exp2 arg

  // resident Q B-frags: B[k=d=kk*32+quad*8+j][n=q=nt*16+ln]
  u16x8 qf[2][2];
#pragma unroll
  for (int nt = 0; nt < 2; nt++)
#pragma unroll
    for (int kk = 0; kk < 2; kk++)
      qf[nt][kk] = *(const u16x8*)(Qh + (size_t)(qw + nt * 16 + ln) * HIDDEN + kk * 32 + quad * 8);

  f32x4 o[4][2];
  f32x4 zero = {0.f, 0.f, 0.f, 0.f};
#pragma unroll
  for (int mtd = 0; mtd < 4; mtd++)
#pragma unroll
    for (int nt = 0; nt < 2; nt++) o[mtd][nt] = zero;
  float mst[2] = {-INFINITY, -INFINITY}, lst[2] = {0.f, 0.f};

  unsigned short* Pw = &Pt2[w][0];
  const unsigned short* vsrc = Vt + (size_t)bh * 16 * (64 * 128);
  const int ldsOff = (w * 4) * 512 + lane * 8;

  // prologue: stage tile 0
#pragma unroll
  for (int i = 0; i < 4; i++)
    gload_lds16(vsrc + ldsOff + i * 512, &VtL[ldsOff + i * 512]);

  for (int kt = 0; kt < 16; ++kt) {
    // ---- S^T = K Q^T
    f32x4 s[8][2];
#pragma unroll
    for (int mt = 0; mt < 8; mt++)
#pragma unroll
      for (int nt = 0; nt < 2; nt++) s[mt][nt] = zero;
#pragma unroll
    for (int mt = 0; mt < 8; mt++) {
      const unsigned short* krow =
          Kh + (size_t)(kt * 128 + mt * 16 + ln) * HIDDEN + quad * 8;
#pragma unroll
      for (int kk = 0; kk < 2; kk++) {
        u16x8 kf = *(const u16x8*)(krow + kk * 32);
#pragma unroll
        for (int nt = 0; nt < 2; nt++)
          s[mt][nt] = __builtin_amdgcn_mfma_f32_16x16x32_bf16(
              __builtin_bit_cast(bf16x8, kf), __builtin_bit_cast(bf16x8, qf[nt][kk]),
              s[mt][nt], 0, 0, 0);
      }
    }
    // ---- column max (per query): in-reg over 32 vals, then 2-shfl quad butterfly
    float alpha[2], mc[2];
#pragma unroll
    for (int nt = 0; nt < 2; nt++) {
      float mx = s[0][nt][0];
#pragma unroll
      for (int mt = 0; mt < 8; mt++)
#pragma unroll
        for (int r = 0; r < 4; r++) mx = fmaxf(mx, s[mt][nt][r]);
      mx = fmaxf(mx, __shfl_xor(mx, 16));
      mx = fmaxf(mx, __shfl_xor(mx, 32));
      float mn = fmaxf(mst[nt], mx);
      alpha[nt] = __builtin_exp2f((mst[nt] - mn) * C1);
      mst[nt] = mn;
      mc[nt] = mn * C1;
    }
    // ---- P = exp2(s*C1 - m*C1), in place
#pragma unroll
    for (int mt = 0; mt < 8; mt++)
#pragma unroll
      for (int nt = 0; nt < 2; nt++)
#pragma unroll
        for (int r = 0; r < 4; r++)
          s[mt][nt][r] = __builtin_exp2f(__builtin_fmaf(s[mt][nt][r], C1, -mc[nt]));
    // ---- column sums + state
#pragma unroll
    for (int nt = 0; nt < 2; nt++) {
      float t = 0.f;
#pragma unroll
      for (int mt = 0; mt < 8; mt++)
#pragma unroll
        for (int r = 0; r < 4; r++) t += s[mt][nt][r];
      t += __shfl_xor(t, 16);
      t += __shfl_xor(t, 32);
      lst[nt] = alpha[nt] * lst[nt] + t;
    }
    // ---- rescale O
#pragma unroll
    for (int mtd = 0; mtd < 4; mtd++)
#pragma unroll
      for (int nt = 0; nt < 2; nt++)
#pragma unroll
        for (int r = 0; r < 4; r++) o[mtd][nt][r] *= alpha[nt];
    // ---- write P^T to per-wave LDS: row=q, col=key (4 keys packed, b64)
#pragma unroll
    for (int nt = 0; nt < 2; nt++)
#pragma unroll
      for (int mt = 0; mt < 8; mt++) {
        unsigned int lo = (unsigned int)bf16_rne(s[mt][nt][0]) |
                          ((unsigned int)bf16_rne(s[mt][nt][1]) << 16);
        unsigned int hi = (unsigned int)bf16_rne(s[mt][nt][2]) |
                          ((unsigned int)bf16_rne(s[mt][nt][3]) << 16);
        uint2 pv; pv.x = lo; pv.y = hi;
        *(uint2*)&Pw[(nt * 16 + ln) * 136 + mt * 16 + quad * 4] = pv;
      }
    __syncthreads();  // B1: Vt dma(kt) drained (vmcnt), all waves ready
    // ---- O^T += V^T P^T
#pragma unroll
    for (int kk = 0; kk < 4; kk++) {
      u16x8 vf[4];
#pragma unroll
      for (int mtd = 0; mtd < 4; mtd++)
        vf[mtd] = *(const u16x8*)&VtL[(mtd * 16 + ln) * 128 + (((kk * 4 + quad) ^ ln) * 8)];
#pragma unroll
      for (int nt = 0; nt < 2; nt++) {
        u16x8 pf = *(const u16x8*)&Pw[(nt * 16 + ln) * 136 + kk * 32 + quad * 8];
#pragma unroll
        for (int mtd = 0; mtd < 4; mtd++)
          o[mtd][nt] = __builtin_amdgcn_mfma_f32_16x16x32_bf16(
              __builtin_bit_cast(bf16x8, vf[mtd]), __builtin_bit_cast(bf16x8, pf),
              o[mtd][nt], 0, 0, 0);
      }
    }
    __syncthreads();  // B2: all PV reads of VtL done -> safe to overwrite
    if (kt < 15) {
      const unsigned short* nsrc = vsrc + (size_t)(kt + 1) * (64 * 128);
#pragma unroll
      for (int i = 0; i < 4; i++)
        gload_lds16(nsrc + ldsOff + i * 512, &VtL[ldsOff + i * 512]);
    }
  }
  __syncthreads();
  // ---- epilogue: O^T (d-major) -> per-wave LDS [q][d] (stride 72) -> coalesced X
  float inv[2];
  inv[0] = 1.0f / lst[0];
  inv[1] = 1.0f / lst[1];
#pragma unroll
  for (int nt = 0; nt < 2; nt++)
#pragma unroll
    for (int mtd = 0; mtd < 4; mtd++) {
      unsigned int lo = (unsigned int)bf16_rne(o[mtd][nt][0] * inv[nt]) |
                        ((unsigned int)bf16_rne(o[mtd][nt][1] * inv[nt]) << 16);
      unsigned int hi = (unsigned int)bf16_rne(o[mtd][nt][2] * inv[nt]) |
                        ((unsigned int)bf16_rne(o[mtd][nt][3] * inv[nt]) << 16);
      uint2 ov; ov.x = lo; ov.y = hi;
      *(uint2*)&Pw[(nt * 16 + ln) * 72 + mtd * 16 + quad * 4] = ov;
    }
  // readback: lane -> row q=lane>>1, d-half=(lane&1)*32; write 64 B per lane
  const int qq = lane >> 1, dh = lane & 1;
  u16x8 r0 = *(const u16x8*)&Pw[qq * 72 + dh * 32];
  u16x8 r1 = *(const u16x8*)&Pw[qq * 72 + dh * 32 + 8];
  u16x8 r2 = *(const u16x8*)&Pw[qq * 72 + dh * 32 + 16];
  u16x8 r3 = *(const u16x8*)&Pw[qq * 72 + dh * 32 + 24];
  unsigned short* dst = X + (size_t)(b * SEQ + qw + qq) * HIDDEN + h * HDIM + dh * 32;
  *(u16x8*)(dst) = r0;
  *(u16x8*)(dst + 8) = r1;
  *(u16x8*)(dst + 16) = r2;
  *(u16x8*)(dst + 24) = r3;
}

// ---------------------------------------------------------------------------
extern "C" void kernel_launch(void* const* d_in, const int* in_sizes, int n_in,
                              void* d_out, int out_size, void* d_ws, size_t ws_size,
                              hipStream_t stream) {
  const float* q_in = (const float*)d_in[0];
  const float* k_in = (const float*)d_in[1];
  const float* v_in = (const float*)d_in[2];
  const float* wq = (const float*)d_in[3];
  const float* bq = (const float*)d_in[4];
  const float* wk = (const float*)d_in[5];
  const float* bk = (const float*)d_in[6];
  const float* wv = (const float*)d_in[7];
  const float* bv = (const float*)d_in[8];
  const float* wf = (const float*)d_in[9];
  const float* bfb = (const float*)d_in[10];

  const size_t NX = (size_t)MTOT * HIDDEN;    // 8.39M elems
  const size_t NW = (size_t)HIDDEN * HIDDEN;  // 1.05M elems
  // Aliased workspace plan (total 5*NX + 4*NW bf16 = ~94 MB):
  //   A: Xq -> (after gemmQ) Vb      B: Xk -> (after gemmK) Vt
  //   C: Xv -> (after gemmV) Xo      W4: weights   Qb, Kb: projections
  unsigned short* A = (unsigned short*)d_ws;
  unsigned short* Bx = A + NX;
  unsigned short* C = Bx + NX;
  unsigned short* W4 = C + NX;
  unsigned short* Qb = W4 + 4 * NW;
  unsigned short* Kb = Qb + NX;

  cvt3<<<dim3(NX / 1024, 3), 256, 0, stream>>>(q_in, k_in, v_in, A, (int)NX);
  cvt4<<<dim3(NW / 1024, 4), 256, 0, stream>>>(wq, wk, wv, wf, W4, (int)NW);

  dim3 gg(HIDDEN / 128, MTOT / 128);  // (8, 64)
  gemm_bt<true><<<gg, 256, 0, stream>>>(A, W4 + 0 * NW, bq, (void*)Qb, MTOT, HIDDEN, HIDDEN);
  gemm_bt<true><<<gg, 256, 0, stream>>>(Bx, W4 + 1 * NW, bk, (void*)Kb, MTOT, HIDDEN, HIDDEN);
  gemm_bt<true><<<gg, 256, 0, stream>>>(C, W4 + 2 * NW, bv, (void*)A, MTOT, HIDDEN, HIDDEN);
  transpose_v<<<1024, 256, 0, stream>>>(A, Bx);
  attn2<<<dim3(SEQ / 128, NHEADS * 4), 256, 0, stream>>>(Qb, Kb, Bx, C);
  gemm_bt<false><<<gg, 256, 0, stream>>>(C, W4 + 3 * NW, bfb, d_out, MTOT, HIDDEN, HIDDEN);
}

// Round 5
// 434.493 us; speedup vs baseline: 1.3768x; 1.2120x over previous
//
#include <hip/hip_runtime.h>
#include <stdint.h>

#define SEQ 2048
#define HIDDEN 1024
#define NHEADS 16
#define HDIM 64
#define MTOT 8192  // B*SEQ

typedef __bf16 bf16x8 __attribute__((ext_vector_type(8)));
typedef unsigned short u16x8 __attribute__((ext_vector_type(8)));
typedef short s16x4 __attribute__((ext_vector_type(4)));
typedef float f32x4 __attribute__((ext_vector_type(4)));

#define GAS __attribute__((address_space(1)))
#define LAS __attribute__((address_space(3)))

__device__ __forceinline__ unsigned short bf16_rne(float f) {
  union { float f; unsigned int u; } v; v.f = f;
  return (unsigned short)((v.u + 0x7fffu + ((v.u >> 16) & 1u)) >> 16);
}

// pack 4 f32 -> 4 bf16 (s16x4)
__device__ __forceinline__ s16x4 pack4_bf16(float a, float b, float c, float d) {
  s16x4 r;
  r[0] = (short)bf16_rne(a); r[1] = (short)bf16_rne(b);
  r[2] = (short)bf16_rne(c); r[3] = (short)bf16_rne(d);
  return r;
}

__device__ __forceinline__ u16x8 cat8(s16x4 a, s16x4 b) {
  u16x8 r;
  r[0] = (unsigned short)a[0]; r[1] = (unsigned short)a[1];
  r[2] = (unsigned short)a[2]; r[3] = (unsigned short)a[3];
  r[4] = (unsigned short)b[0]; r[5] = (unsigned short)b[1];
  r[6] = (unsigned short)b[2]; r[7] = (unsigned short)b[3];
  return r;
}

__device__ __forceinline__ void gload_lds16(const unsigned short* g, unsigned short* l) {
  __builtin_amdgcn_global_load_lds((GAS void*)(unsigned short*)g, (LAS void*)l, 16, 0, 0);
}

// ---------------- fused fp32 -> bf16 conversions ---------------------------
__global__ __launch_bounds__(256) void cvt3(const float* __restrict__ a,
                                            const float* __restrict__ b,
                                            const float* __restrict__ c,
                                            unsigned short* __restrict__ out,
                                            int perSeg) {
  const int seg = blockIdx.y;
  const float* in = seg == 0 ? a : (seg == 1 ? b : c);
  int i = blockIdx.x * 256 + threadIdx.x;
  float4 v = ((const float4*)in)[i];
  ushort4 o;
  o.x = bf16_rne(v.x); o.y = bf16_rne(v.y);
  o.z = bf16_rne(v.z); o.w = bf16_rne(v.w);
  ((ushort4*)(out + (size_t)seg * perSeg))[i] = o;
}

__global__ __launch_bounds__(256) void cvt4(const float* __restrict__ a,
                                            const float* __restrict__ b,
                                            const float* __restrict__ c,
                                            const float* __restrict__ d,
                                            unsigned short* __restrict__ out,
                                            int perSeg) {
  const int seg = blockIdx.y;
  const float* in = seg == 0 ? a : (seg == 1 ? b : (seg == 2 ? c : d));
  int i = blockIdx.x * 256 + threadIdx.x;
  float4 v = ((const float4*)in)[i];
  ushort4 o;
  o.x = bf16_rne(v.x); o.y = bf16_rne(v.y);
  o.z = bf16_rne(v.z); o.w = bf16_rne(v.w);
  ((ushort4*)(out + (size_t)seg * perSeg))[i] = o;
}

// ---------------- fused QKV GEMM -------------------------------------------
// grid.x = 24: segment seg = bx>>3 selects (input, weight rows, bias, output).
// W rows 0-1023 = wq, 1024-2047 = wk, 2048-3071 = wv (contiguous in W4).
__global__ __launch_bounds__(256) void gemm_qkv(const unsigned short* __restrict__ Xq,
                                                const unsigned short* __restrict__ Xk,
                                                const unsigned short* __restrict__ Xv,
                                                const unsigned short* __restrict__ W,
                                                const float* __restrict__ bq,
                                                const float* __restrict__ bk,
                                                const float* __restrict__ bv,
                                                unsigned short* __restrict__ Qb,
                                                unsigned short* __restrict__ Kb,
                                                unsigned short* __restrict__ Vb) {
  __shared__ unsigned short As[128 * 32];
  __shared__ unsigned short Bs[128 * 32];
  const int tid = threadIdx.x;
  const int lane = tid & 63, w = tid >> 6;
  const int quad = lane >> 4, ln = lane & 15;
  const int wm = w & 1, wn = w >> 1;
  const int mBase = blockIdx.y * 128, nBase = blockIdx.x * 128;
  const int seg = blockIdx.x >> 3;
  const unsigned short* A = seg == 0 ? Xq : (seg == 1 ? Xk : Xv);
  const float* bias = seg == 0 ? bq : (seg == 1 ? bk : bv);
  unsigned short* outp = seg == 0 ? Qb : (seg == 1 ? Kb : Vb);
  const int K = HIDDEN;

  f32x4 acc[4][4];
  f32x4 zero = {0.f, 0.f, 0.f, 0.f};
#pragma unroll
  for (int i = 0; i < 4; i++)
#pragma unroll
    for (int j = 0; j < 4; j++) acc[i][j] = zero;

  const int e0 = tid * 8;
  const int e1 = (256 + tid) * 8;
  const int r0 = e0 >> 5, c0 = e0 & 31;
  const int r1 = e1 >> 5, c1 = e1 & 31;
  const unsigned short* Ap0 = A + (size_t)(mBase + r0) * K + c0;
  const unsigned short* Ap1 = A + (size_t)(mBase + r1) * K + c1;
  const unsigned short* Wp0 = W + (size_t)(nBase + r0) * K + c0;
  const unsigned short* Wp1 = W + (size_t)(nBase + r1) * K + c1;

  for (int k0 = 0; k0 < K; k0 += 32) {
    gload_lds16(Ap0 + k0, &As[e0]);
    gload_lds16(Ap1 + k0, &As[e1]);
    gload_lds16(Wp0 + k0, &Bs[e0]);
    gload_lds16(Wp1 + k0, &Bs[e1]);
    __syncthreads();
    u16x8 af[4], bfr[4];
#pragma unroll
    for (int mi = 0; mi < 4; mi++)
      af[mi] = *(const u16x8*)&As[(wm * 64 + mi * 16 + ln) * 32 + quad * 8];
#pragma unroll
    for (int ni = 0; ni < 4; ni++)
      bfr[ni] = *(const u16x8*)&Bs[(wn * 64 + ni * 16 + ln) * 32 + quad * 8];
#pragma unroll
    for (int mi = 0; mi < 4; mi++)
#pragma unroll
      for (int ni = 0; ni < 4; ni++)
        acc[mi][ni] = __builtin_amdgcn_mfma_f32_16x16x32_bf16(
            __builtin_bit_cast(bf16x8, af[mi]), __builtin_bit_cast(bf16x8, bfr[ni]),
            acc[mi][ni], 0, 0, 0);
    __syncthreads();
  }

#pragma unroll
  for (int ni = 0; ni < 4; ni++) {
    const int colg = nBase + wn * 64 + ni * 16 + ln;
    const int col = colg & 1023;
    const float bvv = bias[col];
#pragma unroll
    for (int mi = 0; mi < 4; mi++) {
      const int row = mBase + wm * 64 + mi * 16 + quad * 4;
#pragma unroll
      for (int r = 0; r < 4; r++)
        outp[(size_t)(row + r) * HIDDEN + col] = bf16_rne(acc[mi][ni][r] + bvv);
    }
  }
}

// ---------------- final GEMM (fp32 out) ------------------------------------
__global__ __launch_bounds__(256) void gemm_f(const unsigned short* __restrict__ A,
                                              const unsigned short* __restrict__ W,
                                              const float* __restrict__ bias,
                                              float* __restrict__ Cv) {
  __shared__ unsigned short As[128 * 32];
  __shared__ unsigned short Bs[128 * 32];
  const int tid = threadIdx.x;
  const int lane = tid & 63, w = tid >> 6;
  const int quad = lane >> 4, ln = lane & 15;
  const int wm = w & 1, wn = w >> 1;
  const int mBase = blockIdx.y * 128, nBase = blockIdx.x * 128;
  const int K = HIDDEN, N = HIDDEN;

  f32x4 acc[4][4];
  f32x4 zero = {0.f, 0.f, 0.f, 0.f};
#pragma unroll
  for (int i = 0; i < 4; i++)
#pragma unroll
    for (int j = 0; j < 4; j++) acc[i][j] = zero;

  const int e0 = tid * 8;
  const int e1 = (256 + tid) * 8;
  const int r0 = e0 >> 5, c0 = e0 & 31;
  const int r1 = e1 >> 5, c1 = e1 & 31;
  const unsigned short* Ap0 = A + (size_t)(mBase + r0) * K + c0;
  const unsigned short* Ap1 = A + (size_t)(mBase + r1) * K + c1;
  const unsigned short* Wp0 = W + (size_t)(nBase + r0) * K + c0;
  const unsigned short* Wp1 = W + (size_t)(nBase + r1) * K + c1;

  for (int k0 = 0; k0 < K; k0 += 32) {
    gload_lds16(Ap0 + k0, &As[e0]);
    gload_lds16(Ap1 + k0, &As[e1]);
    gload_lds16(Wp0 + k0, &Bs[e0]);
    gload_lds16(Wp1 + k0, &Bs[e1]);
    __syncthreads();
    u16x8 af[4], bfr[4];
#pragma unroll
    for (int mi = 0; mi < 4; mi++)
      af[mi] = *(const u16x8*)&As[(wm * 64 + mi * 16 + ln) * 32 + quad * 8];
#pragma unroll
    for (int ni = 0; ni < 4; ni++)
      bfr[ni] = *(const u16x8*)&Bs[(wn * 64 + ni * 16 + ln) * 32 + quad * 8];
#pragma unroll
    for (int mi = 0; mi < 4; mi++)
#pragma unroll
      for (int ni = 0; ni < 4; ni++)
        acc[mi][ni] = __builtin_amdgcn_mfma_f32_16x16x32_bf16(
            __builtin_bit_cast(bf16x8, af[mi]), __builtin_bit_cast(bf16x8, bfr[ni]),
            acc[mi][ni], 0, 0, 0);
    __syncthreads();
  }

#pragma unroll
  for (int ni = 0; ni < 4; ni++) {
    const int col = nBase + wn * 64 + ni * 16 + ln;
    const float bvv = bias[col];
#pragma unroll
    for (int mi = 0; mi < 4; mi++) {
      const int row = mBase + wm * 64 + mi * 16 + quad * 4;
#pragma unroll
      for (int r = 0; r < 4; r++)
        Cv[(size_t)(row + r) * N + col] = acc[mi][ni][r] + bvv;
    }
  }
}

// ---------------- V transpose: per-tile, PV-permuted, swizzled chunks ------
// element j of granule G=g*4+Phi (at row d, slot G^(d&15)) holds
// V[key kt*128 + g*32 + (j>>2)*16 + Phi*4 + (j&3)][d].
__global__ __launch_bounds__(256) void transpose_v(const unsigned short* __restrict__ Vb,
                                                   unsigned short* __restrict__ Vt) {
  __shared__ unsigned short L[128 * 88];
  const int t = blockIdx.x;  // 1024 tiles
  const int bh = t >> 4, kt = t & 15;
  const int b = bh >> 4, h = bh & 15;
  const int tid = threadIdx.x;
  {
    const int key = tid >> 1, hf = tid & 1;
    const unsigned short* src =
        Vb + ((size_t)(b * SEQ + kt * 128 + key)) * HIDDEN + h * HDIM + hf * 32;
    u16x8 a0 = *(const u16x8*)(src);
    u16x8 a1 = *(const u16x8*)(src + 8);
    u16x8 a2 = *(const u16x8*)(src + 16);
    u16x8 a3 = *(const u16x8*)(src + 24);
    unsigned short* dst = &L[key * 88 + hf * 32];
    *(u16x8*)(dst) = a0;
    *(u16x8*)(dst + 8) = a1;
    *(u16x8*)(dst + 16) = a2;
    *(u16x8*)(dst + 24) = a3;
  }
  __syncthreads();
  const int d = tid & 63, w = tid >> 6;
  unsigned short* out = Vt + (size_t)t * (64 * 128);
#pragma unroll
  for (int gg = 0; gg < 4; gg++) {
    const int G = w * 4 + gg;
    const int g = G >> 2, Phi = G & 3;
    u16x8 v;
#pragma unroll
    for (int j = 0; j < 8; j++) {
      const int kk = g * 32 + (j >> 2) * 16 + Phi * 4 + (j & 3);
      v[j] = L[kk * 88 + d];
    }
    *(u16x8*)(out + d * 128 + ((G ^ (d & 15)) * 8)) = v;
  }
}

// ---------------- flash attention v4: no-max softmax, permuted PV ----------
// S^T = K.Q^T (16x16x32; C: key=quad*4+r, query=ln). P=exp2(S*C1) packed in
// regs; pairs of 16-key tiles concatenate in-lane into 16x16x32 B-frags under
// the kk(g,Phi,j) permutation baked into Vt. O^T += V^T.P^T (16x16x32, V^T
// A-frags b128 from swizzled double-buffered LDS). 1 barrier/tile, no shfl
// in loop; denominators from per-lane partials reduced once at end.
__global__ __launch_bounds__(256, 3) void attn4(const unsigned short* __restrict__ Q,
                                                const unsigned short* __restrict__ K,
                                                const unsigned short* __restrict__ Vt,
                                                unsigned short* __restrict__ X) {
  __shared__ unsigned short VtL[2][64 * 128];  // 2 x 16 KB
  const int tid = threadIdx.x, lane = tid & 63, w = tid >> 6;
  const int quad = lane >> 4, ln = lane & 15;
  const int bh = blockIdx.y, b = bh >> 4, h = bh & 15;
  const size_t base = (size_t)b * SEQ * HIDDEN + (size_t)h * HDIM;
  const unsigned short* Qh = Q + base;
  const unsigned short* Kh = K + base;
  const int qw = blockIdx.x * 128 + w * 32;
  const float C1 = 0.125f * 1.44269504088896f;

  u16x8 qf[2][2];
#pragma unroll
  for (int nt = 0; nt < 2; nt++)
#pragma unroll
    for (int kk2 = 0; kk2 < 2; kk2++)
      qf[nt][kk2] = *(const u16x8*)(Qh + (size_t)(qw + nt * 16 + ln) * HIDDEN + kk2 * 32 + quad * 8);

  f32x4 o[4][2];
  f32x4 zero = {0.f, 0.f, 0.f, 0.f};
#pragma unroll
  for (int mtd = 0; mtd < 4; mtd++)
#pragma unroll
    for (int nt = 0; nt < 2; nt++) o[mtd][nt] = zero;
  f32x4 lacc[2] = {zero, zero};

  const unsigned short* vsrc = Vt + (size_t)bh * 16 * (64 * 128);
  const int ldsOff = w * 2048 + lane * 8;  // lane*16B matches DMA lane scatter
  const unsigned short* Kl = Kh + (size_t)ln * HIDDEN + quad * 8;

#pragma unroll
  for (int i = 0; i < 4; i++)
    gload_lds16(vsrc + ldsOff + i * 512, &VtL[0][ldsOff + i * 512]);

  for (int kt = 0; kt < 16; ++kt) {
    s16x4 p4[8][2];
#pragma unroll
    for (int mt = 0; mt < 8; mt++) {
      const size_t koff = (size_t)(kt * 128 + mt * 16) * HIDDEN;  // wave-uniform
      u16x8 kf0 = *(const u16x8*)(Kl + koff);
      u16x8 kf1 = *(const u16x8*)(Kl + koff + 32);
      f32x4 s0 = zero, s1 = zero;
      s0 = __builtin_amdgcn_mfma_f32_16x16x32_bf16(
          __builtin_bit_cast(bf16x8, kf0), __builtin_bit_cast(bf16x8, qf[0][0]), s0, 0, 0, 0);
      s0 = __builtin_amdgcn_mfma_f32_16x16x32_bf16(
          __builtin_bit_cast(bf16x8, kf1), __builtin_bit_cast(bf16x8, qf[0][1]), s0, 0, 0, 0);
      s1 = __builtin_amdgcn_mfma_f32_16x16x32_bf16(
          __builtin_bit_cast(bf16x8, kf0), __builtin_bit_cast(bf16x8, qf[1][0]), s1, 0, 0, 0);
      s1 = __builtin_amdgcn_mfma_f32_16x16x32_bf16(
          __builtin_bit_cast(bf16x8, kf1), __builtin_bit_cast(bf16x8, qf[1][1]), s1, 0, 0, 0);
      float e0[4], e1[4];
#pragma unroll
      for (int r = 0; r < 4; r++) {
        e0[r] = __builtin_exp2f(s0[r] * C1);
        e1[r] = __builtin_exp2f(s1[r] * C1);
        lacc[0][r] += e0[r];
        lacc[1][r] += e1[r];
      }
      p4[mt][0] = pack4_bf16(e0[0], e0[1], e0[2], e0[3]);
      p4[mt][1] = pack4_bf16(e1[0], e1[1], e1[2], e1[3]);
    }
    __syncthreads();  // all waves' DMA(kt) drained; PV(kt-1) LDS reads done
    if (kt < 15) {
      const unsigned short* nsrc = vsrc + (size_t)(kt + 1) * (64 * 128);
      unsigned short* nbuf = &VtL[(kt + 1) & 1][0];
#pragma unroll
      for (int i = 0; i < 4; i++)
        gload_lds16(nsrc + ldsOff + i * 512, &nbuf[ldsOff + i * 512]);
    }
    const unsigned short* vb = &VtL[kt & 1][0];
#pragma unroll
    for (int g = 0; g < 4; g++) {
      u16x8 P8[2];
      P8[0] = cat8(p4[2 * g][0], p4[2 * g + 1][0]);
      P8[1] = cat8(p4[2 * g][1], p4[2 * g + 1][1]);
      u16x8 vf[4];
#pragma unroll
      for (int mtd = 0; mtd < 4; mtd++)
        vf[mtd] = *(const u16x8*)&vb[(mtd * 16 + ln) * 128 + (((g * 4 + quad) ^ ln) * 8)];
#pragma unroll
      for (int nt = 0; nt < 2; nt++)
#pragma unroll
        for (int mtd = 0; mtd < 4; mtd++)
          o[mtd][nt] = __builtin_amdgcn_mfma_f32_16x16x32_bf16(
              __builtin_bit_cast(bf16x8, vf[mtd]), __builtin_bit_cast(bf16x8, P8[nt]),
              o[mtd][nt], 0, 0, 0);
    }
  }

  float inv[2];
#pragma unroll
  for (int nt = 0; nt < 2; nt++) {
    float l = lacc[nt][0] + lacc[nt][1] + lacc[nt][2] + lacc[nt][3];
    l += __shfl_xor(l, 16);
    l += __shfl_xor(l, 32);
    inv[nt] = 1.0f / l;
  }
#pragma unroll
  for (int nt = 0; nt < 2; nt++) {
    unsigned short* dst = X + (size_t)(b * SEQ + qw + nt * 16 + ln) * HIDDEN + h * HDIM;
#pragma unroll
    for (int mtd = 0; mtd < 4; mtd++) {
      s16x4 ov = pack4_bf16(o[mtd][nt][0] * inv[nt], o[mtd][nt][1] * inv[nt],
                            o[mtd][nt][2] * inv[nt], o[mtd][nt][3] * inv[nt]);
      *(s16x4*)(dst + mtd * 16 + quad * 4) = ov;
    }
  }
}

// ---------------------------------------------------------------------------
extern "C" void kernel_launch(void* const* d_in, const int* in_sizes, int n_in,
                              void* d_out, int out_size, void* d_ws, size_t ws_size,
                              hipStream_t stream) {
  const float* q_in = (const float*)d_in[0];
  const float* k_in = (const float*)d_in[1];
  const float* v_in = (const float*)d_in[2];
  const float* wq = (const float*)d_in[3];
  const float* bq = (const float*)d_in[4];
  const float* wk = (const float*)d_in[5];
  const float* bk = (const float*)d_in[6];
  const float* wv = (const float*)d_in[7];
  const float* bv = (const float*)d_in[8];
  const float* wf = (const float*)d_in[9];
  const float* bfb = (const float*)d_in[10];

  const size_t NX = (size_t)MTOT * HIDDEN;
  const size_t NW = (size_t)HIDDEN * HIDDEN;
  // A=x_q, Bx=x_k (later Vt), C=x_v (later attn out), W4, Qb, Kb, Vb  (~109 MB)
  unsigned short* A = (unsigned short*)d_ws;
  unsigned short* Bx = A + NX;
  unsigned short* C = Bx + NX;
  unsigned short* W4 = C + NX;
  unsigned short* Qb = W4 + 4 * NW;
  unsigned short* Kb = Qb + NX;
  unsigned short* Vb = Kb + NX;

  cvt3<<<dim3(NX / 1024, 3), 256, 0, stream>>>(q_in, k_in, v_in, A, (int)NX);
  cvt4<<<dim3(NW / 1024, 4), 256, 0, stream>>>(wq, wk, wv, wf, W4, (int)NW);

  gemm_qkv<<<dim3(24, MTOT / 128), 256, 0, stream>>>(A, Bx, C, W4, bq, bk, bv, Qb, Kb, Vb);
  transpose_v<<<1024, 256, 0, stream>>>(Vb, Bx);
  attn4<<<dim3(SEQ / 128, NHEADS * 4), 256, 0, stream>>>(Qb, Kb, Bx, C);
  gemm_f<<<dim3(8, MTOT / 128), 256, 0, stream>>>(C, W4 + 3 * NW, bfb, (float*)d_out);
}

// Round 6
// 410.172 us; speedup vs baseline: 1.4584x; 1.0593x over previous
//
#include <hip/hip_runtime.h>
#include <stdint.h>

#define SEQ 2048
#define HIDDEN 1024
#define NHEADS 16
#define HDIM 64
#define MTOT 8192  // B*SEQ

// 1/sqrt(HDIM) * log2(e), folded into wq/bq so attn does exp2(S) directly
#define C1SCALE 0.1803368801111437f

typedef __bf16 bf16x8 __attribute__((ext_vector_type(8)));
typedef unsigned short u16x8 __attribute__((ext_vector_type(8)));
typedef short s16x4 __attribute__((ext_vector_type(4)));
typedef unsigned int u32x4 __attribute__((ext_vector_type(4)));
typedef float f32x4 __attribute__((ext_vector_type(4)));

#define GAS __attribute__((address_space(1)))
#define LAS __attribute__((address_space(3)))

__device__ __forceinline__ unsigned short bf16_rne(float f) {
  union { float f; unsigned int u; } v; v.f = f;
  return (unsigned short)((v.u + 0x7fffu + ((v.u >> 16) & 1u)) >> 16);
}

// pack 2 f32 -> 2 bf16 in one dword: round-half-up adds + one v_perm_b32
__device__ __forceinline__ unsigned int pk2(float lo, float hi) {
  unsigned int a = __builtin_bit_cast(unsigned int, hi) + 0x8000u;  // high short
  unsigned int b = __builtin_bit_cast(unsigned int, lo) + 0x8000u;  // low short
  return __builtin_amdgcn_perm(a, b, 0x07060302u);
}

__device__ __forceinline__ s16x4 pack4_bf16(float a, float b, float c, float d) {
  s16x4 r;
  r[0] = (short)bf16_rne(a); r[1] = (short)bf16_rne(b);
  r[2] = (short)bf16_rne(c); r[3] = (short)bf16_rne(d);
  return r;
}

__device__ __forceinline__ void gload_lds16(const unsigned short* g, unsigned short* l) {
  __builtin_amdgcn_global_load_lds((GAS void*)(unsigned short*)g, (LAS void*)l, 16, 0, 0);
}

// ---------------- fused fp32 -> bf16 conversions ---------------------------
__global__ __launch_bounds__(256) void cvt3(const float* __restrict__ a,
                                            const float* __restrict__ b,
                                            const float* __restrict__ c,
                                            unsigned short* __restrict__ out,
                                            int perSeg) {
  const int seg = blockIdx.y;
  const float* in = seg == 0 ? a : (seg == 1 ? b : c);
  int i = blockIdx.x * 256 + threadIdx.x;
  float4 v = ((const float4*)in)[i];
  ushort4 o;
  o.x = bf16_rne(v.x); o.y = bf16_rne(v.y);
  o.z = bf16_rne(v.z); o.w = bf16_rne(v.w);
  ((ushort4*)(out + (size_t)seg * perSeg))[i] = o;
}

// seg 0 (wq) is pre-scaled by C1SCALE (softmax scale folded into Q projection)
__global__ __launch_bounds__(256) void cvt4(const float* __restrict__ a,
                                            const float* __restrict__ b,
                                            const float* __restrict__ c,
                                            const float* __restrict__ d,
                                            unsigned short* __restrict__ out,
                                            int perSeg) {
  const int seg = blockIdx.y;
  const float* in = seg == 0 ? a : (seg == 1 ? b : (seg == 2 ? c : d));
  const float sc = (seg == 0) ? C1SCALE : 1.0f;
  int i = blockIdx.x * 256 + threadIdx.x;
  float4 v = ((const float4*)in)[i];
  ushort4 o;
  o.x = bf16_rne(v.x * sc); o.y = bf16_rne(v.y * sc);
  o.z = bf16_rne(v.z * sc); o.w = bf16_rne(v.w * sc);
  ((ushort4*)(out + (size_t)seg * perSeg))[i] = o;
}

// ---------------- fused QKV GEMM -------------------------------------------
// grid.x = 24: seg = bx>>3 selects (input, weight rows, bias, output).
// seg 0 bias scaled by C1SCALE (weights already pre-scaled in cvt4).
__global__ __launch_bounds__(256) void gemm_qkv(const unsigned short* __restrict__ Xq,
                                                const unsigned short* __restrict__ Xk,
                                                const unsigned short* __restrict__ Xv,
                                                const unsigned short* __restrict__ W,
                                                const float* __restrict__ bq,
                                                const float* __restrict__ bk,
                                                const float* __restrict__ bv,
                                                unsigned short* __restrict__ Qb,
                                                unsigned short* __restrict__ Kb,
                                                unsigned short* __restrict__ Vb) {
  __shared__ unsigned short As[128 * 32];
  __shared__ unsigned short Bs[128 * 32];
  const int tid = threadIdx.x;
  const int lane = tid & 63, w = tid >> 6;
  const int quad = lane >> 4, ln = lane & 15;
  const int wm = w & 1, wn = w >> 1;
  const int mBase = blockIdx.y * 128, nBase = blockIdx.x * 128;
  const int seg = blockIdx.x >> 3;
  const unsigned short* A = seg == 0 ? Xq : (seg == 1 ? Xk : Xv);
  const float* bias = seg == 0 ? bq : (seg == 1 ? bk : bv);
  const float bscale = seg == 0 ? C1SCALE : 1.0f;
  unsigned short* outp = seg == 0 ? Qb : (seg == 1 ? Kb : Vb);
  const int K = HIDDEN;

  f32x4 acc[4][4];
  f32x4 zero = {0.f, 0.f, 0.f, 0.f};
#pragma unroll
  for (int i = 0; i < 4; i++)
#pragma unroll
    for (int j = 0; j < 4; j++) acc[i][j] = zero;

  const int e0 = tid * 8;
  const int e1 = (256 + tid) * 8;
  const int r0 = e0 >> 5, c0 = e0 & 31;
  const int r1 = e1 >> 5, c1 = e1 & 31;
  const unsigned short* Ap0 = A + (size_t)(mBase + r0) * K + c0;
  const unsigned short* Ap1 = A + (size_t)(mBase + r1) * K + c1;
  const unsigned short* Wp0 = W + (size_t)(nBase + r0) * K + c0;
  const unsigned short* Wp1 = W + (size_t)(nBase + r1) * K + c1;

  for (int k0 = 0; k0 < K; k0 += 32) {
    gload_lds16(Ap0 + k0, &As[e0]);
    gload_lds16(Ap1 + k0, &As[e1]);
    gload_lds16(Wp0 + k0, &Bs[e0]);
    gload_lds16(Wp1 + k0, &Bs[e1]);
    __syncthreads();
    u16x8 af[4], bfr[4];
#pragma unroll
    for (int mi = 0; mi < 4; mi++)
      af[mi] = *(const u16x8*)&As[(wm * 64 + mi * 16 + ln) * 32 + quad * 8];
#pragma unroll
    for (int ni = 0; ni < 4; ni++)
      bfr[ni] = *(const u16x8*)&Bs[(wn * 64 + ni * 16 + ln) * 32 + quad * 8];
#pragma unroll
    for (int mi = 0; mi < 4; mi++)
#pragma unroll
      for (int ni = 0; ni < 4; ni++)
        acc[mi][ni] = __builtin_amdgcn_mfma_f32_16x16x32_bf16(
            __builtin_bit_cast(bf16x8, af[mi]), __builtin_bit_cast(bf16x8, bfr[ni]),
            acc[mi][ni], 0, 0, 0);
    __syncthreads();
  }

#pragma unroll
  for (int ni = 0; ni < 4; ni++) {
    const int colg = nBase + wn * 64 + ni * 16 + ln;
    const int col = colg & 1023;
    const float bvv = bias[col] * bscale;
#pragma unroll
    for (int mi = 0; mi < 4; mi++) {
      const int row = mBase + wm * 64 + mi * 16 + quad * 4;
#pragma unroll
      for (int r = 0; r < 4; r++)
        outp[(size_t)(row + r) * HIDDEN + col] = bf16_rne(acc[mi][ni][r] + bvv);
    }
  }
}

// ---------------- final GEMM (fp32 out) ------------------------------------
__global__ __launch_bounds__(256) void gemm_f(const unsigned short* __restrict__ A,
                                              const unsigned short* __restrict__ W,
                                              const float* __restrict__ bias,
                                              float* __restrict__ Cv) {
  __shared__ unsigned short As[128 * 32];
  __shared__ unsigned short Bs[128 * 32];
  const int tid = threadIdx.x;
  const int lane = tid & 63, w = tid >> 6;
  const int quad = lane >> 4, ln = lane & 15;
  const int wm = w & 1, wn = w >> 1;
  const int mBase = blockIdx.y * 128, nBase = blockIdx.x * 128;
  const int K = HIDDEN, N = HIDDEN;

  f32x4 acc[4][4];
  f32x4 zero = {0.f, 0.f, 0.f, 0.f};
#pragma unroll
  for (int i = 0; i < 4; i++)
#pragma unroll
    for (int j = 0; j < 4; j++) acc[i][j] = zero;

  const int e0 = tid * 8;
  const int e1 = (256 + tid) * 8;
  const int r0 = e0 >> 5, c0 = e0 & 31;
  const int r1 = e1 >> 5, c1 = e1 & 31;
  const unsigned short* Ap0 = A + (size_t)(mBase + r0) * K + c0;
  const unsigned short* Ap1 = A + (size_t)(mBase + r1) * K + c1;
  const unsigned short* Wp0 = W + (size_t)(nBase + r0) * K + c0;
  const unsigned short* Wp1 = W + (size_t)(nBase + r1) * K + c1;

  for (int k0 = 0; k0 < K; k0 += 32) {
    gload_lds16(Ap0 + k0, &As[e0]);
    gload_lds16(Ap1 + k0, &As[e1]);
    gload_lds16(Wp0 + k0, &Bs[e0]);
    gload_lds16(Wp1 + k0, &Bs[e1]);
    __syncthreads();
    u16x8 af[4], bfr[4];
#pragma unroll
    for (int mi = 0; mi < 4; mi++)
      af[mi] = *(const u16x8*)&As[(wm * 64 + mi * 16 + ln) * 32 + quad * 8];
#pragma unroll
    for (int ni = 0; ni < 4; ni++)
      bfr[ni] = *(const u16x8*)&Bs[(wn * 64 + ni * 16 + ln) * 32 + quad * 8];
#pragma unroll
    for (int mi = 0; mi < 4; mi++)
#pragma unroll
      for (int ni = 0; ni < 4; ni++)
        acc[mi][ni] = __builtin_amdgcn_mfma_f32_16x16x32_bf16(
            __builtin_bit_cast(bf16x8, af[mi]), __builtin_bit_cast(bf16x8, bfr[ni]),
            acc[mi][ni], 0, 0, 0);
    __syncthreads();
  }

#pragma unroll
  for (int ni = 0; ni < 4; ni++) {
    const int col = nBase + wn * 64 + ni * 16 + ln;
    const float bvv = bias[col];
#pragma unroll
    for (int mi = 0; mi < 4; mi++) {
      const int row = mBase + wm * 64 + mi * 16 + quad * 4;
#pragma unroll
      for (int r = 0; r < 4; r++)
        Cv[(size_t)(row + r) * N + col] = acc[mi][ni][r] + bvv;
    }
  }
}

// ---------------- V transpose: per-tile, PV-permuted, swizzled chunks ------
__global__ __launch_bounds__(256) void transpose_v(const unsigned short* __restrict__ Vb,
                                                   unsigned short* __restrict__ Vt) {
  __shared__ unsigned short L[128 * 88];
  const int t = blockIdx.x;  // 1024 tiles
  const int bh = t >> 4, kt = t & 15;
  const int b = bh >> 4, h = bh & 15;
  const int tid = threadIdx.x;
  {
    const int key = tid >> 1, hf = tid & 1;
    const unsigned short* src =
        Vb + ((size_t)(b * SEQ + kt * 128 + key)) * HIDDEN + h * HDIM + hf * 32;
    u16x8 a0 = *(const u16x8*)(src);
    u16x8 a1 = *(const u16x8*)(src + 8);
    u16x8 a2 = *(const u16x8*)(src + 16);
    u16x8 a3 = *(const u16x8*)(src + 24);
    unsigned short* dst = &L[key * 88 + hf * 32];
    *(u16x8*)(dst) = a0;
    *(u16x8*)(dst + 8) = a1;
    *(u16x8*)(dst + 16) = a2;
    *(u16x8*)(dst + 24) = a3;
  }
  __syncthreads();
  const int d = tid & 63, w = tid >> 6;
  unsigned short* out = Vt + (size_t)t * (64 * 128);
#pragma unroll
  for (int gg = 0; gg < 4; gg++) {
    const int G = w * 4 + gg;
    const int g = G >> 2, Phi = G & 3;
    u16x8 v;
#pragma unroll
    for (int j = 0; j < 8; j++) {
      const int kk = g * 32 + (j >> 2) * 16 + Phi * 4 + (j & 3);
      v[j] = L[kk * 88 + d];
    }
    *(u16x8*)(out + d * 128 + ((G ^ (d & 15)) * 8)) = v;
  }
}

// ---------------- flash attention v5 ---------------------------------------
// Q pre-scaled by C1SCALE upstream -> P = exp2(S) directly.
// K loads: depth-4 register prefetch ring (no in-loop load stalls).
// PV(g) interleaved after each mt-pair; P packed via v_perm into u32x4 B-frags.
// 1 barrier/tile; V DMA issued right after barrier (full-iter latency cover).
// Grid: bh = blockIdx.x so same-head q-blocks share an XCD (K L2-resident).
__global__ __launch_bounds__(256, 3) void attn5(const unsigned short* __restrict__ Q,
                                                const unsigned short* __restrict__ K,
                                                const unsigned short* __restrict__ Vt,
                                                unsigned short* __restrict__ X) {
  __shared__ unsigned short VtL[2][64 * 128];  // 2 x 16 KB
  const int tid = threadIdx.x, lane = tid & 63, w = tid >> 6;
  const int quad = lane >> 4, ln = lane & 15;
  const int bh = blockIdx.x, b = bh >> 4, h = bh & 15;
  const size_t base = (size_t)b * SEQ * HIDDEN + (size_t)h * HDIM;
  const unsigned short* Qh = Q + base;
  const unsigned short* Kh = K + base;
  const int qw = blockIdx.y * 128 + w * 32;

  // resident Q B-frags: B[k=d=kk2*32+quad*8+j][n=q=nt*16+ln]
  u16x8 qf[2][2];
#pragma unroll
  for (int nt = 0; nt < 2; nt++)
#pragma unroll
    for (int kk2 = 0; kk2 < 2; kk2++)
      qf[nt][kk2] = *(const u16x8*)(Qh + (size_t)(qw + nt * 16 + ln) * HIDDEN + kk2 * 32 + quad * 8);

  f32x4 o[4][2];
  f32x4 zero = {0.f, 0.f, 0.f, 0.f};
#pragma unroll
  for (int mtd = 0; mtd < 4; mtd++)
#pragma unroll
    for (int nt = 0; nt < 2; nt++) o[mtd][nt] = zero;
  f32x4 lacc[2] = {zero, zero};

  const unsigned short* vsrc = Vt + (size_t)bh * 16 * (64 * 128);
  const int ldsOff = w * 2048 + lane * 8;
  const unsigned short* Kl = Kh + (size_t)ln * HIDDEN + quad * 8;

  // K prefetch ring: slots hold mt, mt+1, mt+2, mt+3 of the rolling sequence
  u16x8 kp[4][2];
#pragma unroll
  for (int m = 0; m < 4; m++) {
    const size_t koff = (size_t)(m * 16) * HIDDEN;
    kp[m][0] = *(const u16x8*)(Kl + koff);
    kp[m][1] = *(const u16x8*)(Kl + koff + 32);
  }
  // V DMA tile 0
#pragma unroll
  for (int i = 0; i < 4; i++)
    gload_lds16(vsrc + ldsOff + i * 512, &VtL[0][ldsOff + i * 512]);

  for (int kt = 0; kt < 16; ++kt) {
    __syncthreads();  // DMA(kt) drained; all waves entered iter kt
    if (kt < 15) {
      const unsigned short* nsrc = vsrc + (size_t)(kt + 1) * (64 * 128);
      unsigned short* nbuf = &VtL[(kt + 1) & 1][0];
#pragma unroll
      for (int i = 0; i < 4; i++)
        gload_lds16(nsrc + ldsOff + i * 512, &nbuf[ldsOff + i * 512]);
    }
    const unsigned short* vb = &VtL[kt & 1][0];
#pragma unroll
    for (int g = 0; g < 4; g++) {
      u32x4 P[2];
#pragma unroll
      for (int half = 0; half < 2; half++) {
        const int mt = 2 * g + half;
        const int slot = mt & 3;
        f32x4 s0 = zero, s1 = zero;
        s0 = __builtin_amdgcn_mfma_f32_16x16x32_bf16(
            __builtin_bit_cast(bf16x8, kp[slot][0]), __builtin_bit_cast(bf16x8, qf[0][0]), s0, 0, 0, 0);
        s0 = __builtin_amdgcn_mfma_f32_16x16x32_bf16(
            __builtin_bit_cast(bf16x8, kp[slot][1]), __builtin_bit_cast(bf16x8, qf[0][1]), s0, 0, 0, 0);
        s1 = __builtin_amdgcn_mfma_f32_16x16x32_bf16(
            __builtin_bit_cast(bf16x8, kp[slot][0]), __builtin_bit_cast(bf16x8, qf[1][0]), s1, 0, 0, 0);
        s1 = __builtin_amdgcn_mfma_f32_16x16x32_bf16(
            __builtin_bit_cast(bf16x8, kp[slot][1]), __builtin_bit_cast(bf16x8, qf[1][1]), s1, 0, 0, 0);
        // refill ring: (kt, mt+4) or (kt+1, mt-4)
        if (mt < 4) {
          const size_t koff = ((size_t)(kt * 128 + (mt + 4) * 16)) * HIDDEN;
          kp[slot][0] = *(const u16x8*)(Kl + koff);
          kp[slot][1] = *(const u16x8*)(Kl + koff + 32);
        } else if (kt < 15) {
          const size_t koff = ((size_t)((kt + 1) * 128 + (mt - 4) * 16)) * HIDDEN;
          kp[slot][0] = *(const u16x8*)(Kl + koff);
          kp[slot][1] = *(const u16x8*)(Kl + koff + 32);
        }
        float e0[4], e1[4];
#pragma unroll
        for (int r = 0; r < 4; r++) {
          e0[r] = __builtin_exp2f(s0[r]);
          e1[r] = __builtin_exp2f(s1[r]);
          lacc[0][r] += e0[r];
          lacc[1][r] += e1[r];
        }
        if (half == 0) {
          P[0][0] = pk2(e0[0], e0[1]); P[0][1] = pk2(e0[2], e0[3]);
          P[1][0] = pk2(e1[0], e1[1]); P[1][1] = pk2(e1[2], e1[3]);
        } else {
          P[0][2] = pk2(e0[0], e0[1]); P[0][3] = pk2(e0[2], e0[3]);
          P[1][2] = pk2(e1[0], e1[1]); P[1][3] = pk2(e1[2], e1[3]);
        }
      }
      // PV for this 32-key group
      u16x8 vf[4];
#pragma unroll
      for (int mtd = 0; mtd < 4; mtd++)
        vf[mtd] = *(const u16x8*)&vb[(mtd * 16 + ln) * 128 + (((g * 4 + quad) ^ ln) * 8)];
#pragma unroll
      for (int nt = 0; nt < 2; nt++) {
        bf16x8 pb = __builtin_bit_cast(bf16x8, P[nt]);
#pragma unroll
        for (int mtd = 0; mtd < 4; mtd++)
          o[mtd][nt] = __builtin_amdgcn_mfma_f32_16x16x32_bf16(
              __builtin_bit_cast(bf16x8, vf[mtd]), pb, o[mtd][nt], 0, 0, 0);
      }
    }
  }

  float inv[2];
#pragma unroll
  for (int nt = 0; nt < 2; nt++) {
    float l = lacc[nt][0] + lacc[nt][1] + lacc[nt][2] + lacc[nt][3];
    l += __shfl_xor(l, 16);
    l += __shfl_xor(l, 32);
    inv[nt] = 1.0f / l;
  }
#pragma unroll
  for (int nt = 0; nt < 2; nt++) {
    unsigned short* dst = X + (size_t)(b * SEQ + qw + nt * 16 + ln) * HIDDEN + h * HDIM;
#pragma unroll
    for (int mtd = 0; mtd < 4; mtd++) {
      s16x4 ov = pack4_bf16(o[mtd][nt][0] * inv[nt], o[mtd][nt][1] * inv[nt],
                            o[mtd][nt][2] * inv[nt], o[mtd][nt][3] * inv[nt]);
      *(s16x4*)(dst + mtd * 16 + quad * 4) = ov;
    }
  }
}

// ---------------------------------------------------------------------------
extern "C" void kernel_launch(void* const* d_in, const int* in_sizes, int n_in,
                              void* d_out, int out_size, void* d_ws, size_t ws_size,
                              hipStream_t stream) {
  const float* q_in = (const float*)d_in[0];
  const float* k_in = (const float*)d_in[1];
  const float* v_in = (const float*)d_in[2];
  const float* wq = (const float*)d_in[3];
  const float* bq = (const float*)d_in[4];
  const float* wk = (const float*)d_in[5];
  const float* bk = (const float*)d_in[6];
  const float* wv = (const float*)d_in[7];
  const float* bv = (const float*)d_in[8];
  const float* wf = (const float*)d_in[9];
  const float* bfb = (const float*)d_in[10];

  const size_t NX = (size_t)MTOT * HIDDEN;
  const size_t NW = (size_t)HIDDEN * HIDDEN;
  unsigned short* A = (unsigned short*)d_ws;
  unsigned short* Bx = A + NX;
  unsigned short* C = Bx + NX;
  unsigned short* W4 = C + NX;
  unsigned short* Qb = W4 + 4 * NW;
  unsigned short* Kb = Qb + NX;
  unsigned short* Vb = Kb + NX;

  cvt3<<<dim3(NX / 1024, 3), 256, 0, stream>>>(q_in, k_in, v_in, A, (int)NX);
  cvt4<<<dim3(NW / 1024, 4), 256, 0, stream>>>(wq, wk, wv, wf, W4, (int)NW);

  gemm_qkv<<<dim3(24, MTOT / 128), 256, 0, stream>>>(A, Bx, C, W4, bq, bk, bv, Qb, Kb, Vb);
  transpose_v<<<1024, 256, 0, stream>>>(Vb, Bx);
  attn5<<<dim3(NHEADS * 4, SEQ / 128), 256, 0, stream>>>(Qb, Kb, Bx, C);
  gemm_f<<<dim3(8, MTOT / 128), 256, 0, stream>>>(C, W4 + 3 * NW, bfb, (float*)d_out);
}